// Round 3
// baseline (153.169 us; speedup 1.0000x reference)
//
#include <hip/hip_runtime.h>

typedef __attribute__((ext_vector_type(8))) short bf16x8;
typedef __attribute__((ext_vector_type(4))) float f32x4;
typedef unsigned short ushort_t;

#define N 4096

__device__ __forceinline__ unsigned short f2bf_rne(float f) {
  unsigned int u = __float_as_uint(f);
  u += 0x7fffu + ((u >> 16) & 1u);   // round-to-nearest-even
  return (unsigned short)(u >> 16);
}

// One block per row (8192 rows: Z then Y). fp32 row norm + bf16 copy.
__global__ __launch_bounds__(256) void prep_kernel(
    const float* __restrict__ Z, const float* __restrict__ Y,
    ushort_t* __restrict__ Zb, ushort_t* __restrict__ Yb,
    float* __restrict__ norms) {
  const int r = blockIdx.x;
  const bool isZ = (r < N);
  const int rr = isZ ? r : r - N;
  const float* __restrict__ src = (isZ ? Z : Y) + (size_t)rr * N;
  ushort_t* __restrict__ dst = (isZ ? Zb : Yb) + (size_t)rr * N;
  const int t = threadIdx.x;

  float s = 0.f;
#pragma unroll
  for (int j = 0; j < 4; ++j) {
    const float4 v = ((const float4*)src)[j * 256 + t];
    s += v.x * v.x + v.y * v.y + v.z * v.z + v.w * v.w;
    short4 o;
    o.x = (short)f2bf_rne(v.x);
    o.y = (short)f2bf_rne(v.y);
    o.z = (short)f2bf_rne(v.z);
    o.w = (short)f2bf_rne(v.w);
    ((short4*)dst)[j * 256 + t] = o;
  }
#pragma unroll
  for (int off = 32; off > 0; off >>= 1) s += __shfl_down(s, off, 64);
  __shared__ float red[4];
  const int lane = t & 63, w = t >> 6;
  if (lane == 0) red[w] = s;
  __syncthreads();
  if (t == 0) norms[r] = sqrtf(red[0] + red[1] + red[2] + red[3]);
}

template <int VM>
__device__ __forceinline__ void vm_wait() {
  if constexpr (VM == 8) asm volatile("s_waitcnt vmcnt(8)" ::: "memory");
  else if constexpr (VM == 4) asm volatile("s_waitcnt vmcnt(4)" ::: "memory");
  else if constexpr (VM == 0) asm volatile("s_waitcnt vmcnt(0)" ::: "memory");
}

// 256x256 tile, BK=32, 8 waves (2M x 4N), 4-deep LDS ring.
// Single barrier region per tile: MFMA(frags T) || ds_read(frags T+1) ||
// stage(tile T+3), then vmcnt(4) + s_barrier. Register-level fragment
// double-buffer (F0/F1 named sets, static indices).
__global__ __launch_bounds__(512, 2) void gemm_kernel(
    const ushort_t* __restrict__ A,   // Zb [N][N]
    const ushort_t* __restrict__ B,   // Yb [N][N]
    const float* __restrict__ norms,  // [2N]: nx then ny
    float* __restrict__ out) {
  __shared__ __align__(16) char smem[131072];  // 4 bufs x (A 16K + B 16K)

  const int bid = blockIdx.x;                 // 256 blocks; 256%8==0: bijective
  const int swz = (bid & 7) * 32 + (bid >> 3);
  const int tile_row = swz >> 4;
  const int tile_col = swz & 15;

  const int tid = threadIdx.x;
  const int l = tid & 63;
  const int w = tid >> 6;
  const int wr = w >> 2;      // M half
  const int wc = w & 3;       // N quarter
  const int li = l & 15;
  const int sl = l >> 4;

  // staging: chunk = q*512 + tid writes LDS bytes [chunk*16,+16) linearly;
  // LDS(row,slot) holds global(row, slot ^ ((row>>1)&3))  [involution]
  const ushort_t* pgA[2];
  const ushort_t* pgB[2];
#pragma unroll
  for (int q = 0; q < 2; ++q) {
    const int ch = q * 512 + tid;
    const int row = ch >> 2, slot = ch & 3;
    const int ss = slot ^ ((row >> 1) & 3);
    pgA[q] = A + (size_t)(tile_row * 256 + row) * N + ss * 8;
    pgB[q] = B + (size_t)(tile_col * 256 + row) * N + ss * 8;
  }

  auto stageA = [&](int t, int buf) {
#pragma unroll
    for (int q = 0; q < 2; ++q)
      __builtin_amdgcn_global_load_lds(
          (__attribute__((address_space(1))) void*)(pgA[q] + t * 32),
          (__attribute__((address_space(3))) void*)(smem + buf * 32768 +
                                                    q * 8192 + w * 1024),
          16, 0, 0);
  };
  auto stageB = [&](int t, int buf) {
#pragma unroll
    for (int q = 0; q < 2; ++q)
      __builtin_amdgcn_global_load_lds(
          (__attribute__((address_space(1))) void*)(pgB[q] + t * 32),
          (__attribute__((address_space(3))) void*)(smem + buf * 32768 + 16384 +
                                                    q * 8192 + w * 1024),
          16, 0, 0);
  };

  // fragment LDS byte offsets: lane reads row base+li, 16B slot sl,
  // swizzled slot = sl ^ ((li>>1)&3)
  const int ssl = sl ^ ((li >> 1) & 3);
  int offA[8], offB[4];
#pragma unroll
  for (int m = 0; m < 8; ++m)
    offA[m] = ((wr * 128 + m * 16 + li) * 32 + ssl * 8) * 2;
#pragma unroll
  for (int n = 0; n < 4; ++n)
    offB[n] = ((wc * 64 + n * 16 + li) * 32 + ssl * 8) * 2;

  f32x4 acc[8][4];
#pragma unroll
  for (int m = 0; m < 8; ++m)
#pragma unroll
    for (int n = 0; n < 4; ++n) acc[m][n] = (f32x4){0.f, 0.f, 0.f, 0.f};

  bf16x8 aF0[8], bF0[4], aF1[8], bF1[4];

  // prologue: stage tiles 0,1,2; vmcnt(4) -> bufs 0,1 resident; prime F0
  stageA(0, 0); stageB(0, 0);
  stageA(1, 1); stageB(1, 1);
  stageA(2, 2); stageB(2, 2);
  vm_wait<4>();
  __builtin_amdgcn_s_barrier();
  __builtin_amdgcn_sched_barrier(0);
#pragma unroll
  for (int m = 0; m < 8; ++m) aF0[m] = *(const bf16x8*)(smem + offA[m]);
#pragma unroll
  for (int n = 0; n < 4; ++n) bF0[n] = *(const bf16x8*)(smem + 16384 + offB[n]);

  // tile body: prefetch frags[T+1] from buf (T+1)&3, stage T+3, MFMA frags[T]
#define TB(T_, AC, BC, AN, BN, BUFN, DOSTAGE, VM, DOBAR)                      \
  {                                                                           \
    const char* pA_ = smem + (BUFN) * 32768;                                  \
    const char* pB_ = pA_ + 16384;                                            \
    _Pragma("unroll")                                                         \
    for (int m = 0; m < 8; ++m) AN[m] = *(const bf16x8*)(pA_ + offA[m]);      \
    _Pragma("unroll")                                                         \
    for (int n = 0; n < 4; ++n) BN[n] = *(const bf16x8*)(pB_ + offB[n]);      \
    if (DOSTAGE) {                                                            \
      stageA((T_) + 3, ((T_) + 3) & 3);                                       \
      stageB((T_) + 3, ((T_) + 3) & 3);                                       \
    }                                                                         \
    __builtin_amdgcn_s_setprio(1);                                            \
    _Pragma("unroll")                                                         \
    for (int m = 0; m < 8; ++m)                                               \
      _Pragma("unroll")                                                       \
      for (int n = 0; n < 4; ++n)                                             \
        acc[m][n] = __builtin_amdgcn_mfma_f32_16x16x32_bf16(AC[m], BC[n],     \
                                                            acc[m][n], 0, 0, 0); \
    __builtin_amdgcn_s_setprio(0);                                            \
    vm_wait<VM>();                                                            \
    if (DOBAR) {                                                              \
      __builtin_amdgcn_s_barrier();                                           \
      __builtin_amdgcn_sched_barrier(0);                                      \
    }                                                                         \
  }

  for (int t = 0; t < 124; t += 4) {
    TB(t + 0, aF0, bF0, aF1, bF1, 1, true, 4, true);
    TB(t + 1, aF1, bF1, aF0, bF0, 2, true, 4, true);
    TB(t + 2, aF0, bF0, aF1, bF1, 3, true, 4, true);
    TB(t + 3, aF1, bF1, aF0, bF0, 0, true, 4, true);
  }
  TB(124, aF0, bF0, aF1, bF1, 1, true, 4, true);    // stages tile 127
  TB(125, aF1, bF1, aF0, bF0, 2, false, 0, true);   // -> 127 resident
  TB(126, aF0, bF0, aF1, bF1, 3, false, -1, false); // last prefetch
#undef TB

  // final tile 127: MFMA only
  __builtin_amdgcn_s_setprio(1);
#pragma unroll
  for (int m = 0; m < 8; ++m)
#pragma unroll
    for (int n = 0; n < 4; ++n)
      acc[m][n] = __builtin_amdgcn_mfma_f32_16x16x32_bf16(aF1[m], bF1[n],
                                                          acc[m][n], 0, 0, 0);
  __builtin_amdgcn_s_setprio(0);

  // epilogue: cosine normalize; C/D layout row=(l>>4)*4+r, col=l&15
  const float* nx = norms;
  const float* ny = norms + N;
  const int row0 = tile_row * 256 + wr * 128 + sl * 4;
  const int col0 = tile_col * 256 + wc * 64 + li;
#pragma unroll
  for (int m = 0; m < 8; ++m) {
#pragma unroll
    for (int r = 0; r < 4; ++r) {
      const int row = row0 + m * 16 + r;
      const float nxr = nx[row];
#pragma unroll
      for (int n = 0; n < 4; ++n) {
        const int col = col0 + n * 16;
        const float denom = fmaxf(nxr * ny[col], 1e-8f);
        out[(size_t)row * N + col] = acc[m][n][r] / denom;
      }
    }
  }
}

extern "C" void kernel_launch(void* const* d_in, const int* in_sizes, int n_in,
                              void* d_out, int out_size, void* d_ws, size_t ws_size,
                              hipStream_t stream) {
  const float* Z = (const float*)d_in[0];
  const float* Y = (const float*)d_in[1];
  float* out = (float*)d_out;

  ushort_t* Zb = (ushort_t*)d_ws;
  ushort_t* Yb = Zb + (size_t)N * N;
  float* norms = (float*)(Yb + (size_t)N * N);

  prep_kernel<<<2 * N, 256, 0, stream>>>(Z, Y, Zb, Yb, norms);
  gemm_kernel<<<(N / 256) * (N / 256), 512, 0, stream>>>(Zb, Yb, norms, out);
}

// Round 4
// 143.484 us; speedup vs baseline: 1.0675x; 1.0675x over previous
//
#include <hip/hip_runtime.h>

typedef __attribute__((ext_vector_type(8))) short bf16x8;
typedef __attribute__((ext_vector_type(4))) float f32x4;
typedef unsigned short ushort_t;

#define N 4096

__device__ __forceinline__ unsigned short f2bf_rne(float f) {
  unsigned int u = __float_as_uint(f);
  u += 0x7fffu + ((u >> 16) & 1u);
  return (unsigned short)(u >> 16);
}

// One block per row (8192 rows: Z then Y). fp32 row norm + bf16 copy.
__global__ __launch_bounds__(256) void prep_kernel(
    const float* __restrict__ Z, const float* __restrict__ Y,
    ushort_t* __restrict__ Zb, ushort_t* __restrict__ Yb,
    float* __restrict__ norms) {
  const int r = blockIdx.x;
  const bool isZ = (r < N);
  const int rr = isZ ? r : r - N;
  const float* __restrict__ src = (isZ ? Z : Y) + (size_t)rr * N;
  ushort_t* __restrict__ dst = (isZ ? Zb : Yb) + (size_t)rr * N;
  const int t = threadIdx.x;

  float s = 0.f;
#pragma unroll
  for (int j = 0; j < 4; ++j) {
    const float4 v = ((const float4*)src)[j * 256 + t];
    s += v.x * v.x + v.y * v.y + v.z * v.z + v.w * v.w;
    short4 o;
    o.x = (short)f2bf_rne(v.x);
    o.y = (short)f2bf_rne(v.y);
    o.z = (short)f2bf_rne(v.z);
    o.w = (short)f2bf_rne(v.w);
    ((short4*)dst)[j * 256 + t] = o;
  }
#pragma unroll
  for (int off = 32; off > 0; off >>= 1) s += __shfl_down(s, off, 64);
  __shared__ float red[4];
  const int lane = t & 63, w = t >> 6;
  if (lane == 0) red[w] = s;
  __syncthreads();
  if (t == 0) norms[r] = sqrtf(red[0] + red[1] + red[2] + red[3]);
}

// ---- 256x256 tile, BK=64, 8 waves (2M x 4N), 2-deep dbuf, 8-phase -------
// LDS buffer layout (per buf, 64KB): A-half0 @0, A-half1 @16384,
//   B-half0 @32768, B-half1 @49152. buf1 = +65536. Row = 128B (64 bf16),
//   8 slots of 16B, swizzle slot ^= (row & 7) (both-sides involution).
__global__ __launch_bounds__(512, 2) void gemm_kernel(
    const ushort_t* __restrict__ A,   // Zb [N][N]
    const ushort_t* __restrict__ B,   // Yb [N][N]
    const float* __restrict__ norms,  // [2N]: nx then ny
    float* __restrict__ out) {
  __shared__ __align__(16) char smem[131072];

  const int bid = blockIdx.x;                 // 256 blocks; bijective
  const int swz = (bid & 7) * 32 + (bid >> 3);
  const int tile_row = swz >> 4;
  const int tile_col = swz & 15;

  const int tid = threadIdx.x;
  const int l = tid & 63;
  const int w = tid >> 6;     // 0..7
  const int wr = w >> 2;      // M half (128 rows)
  const int wc = w & 3;       // N quarter (64 cols)
  const int li = l & 15;
  const int sl = l >> 4;

  // staging: chunk ch = q*512 + tid writes LDS [half_base + ch*16, +16)
  // linearly; LDS(row,slot) holds global(row, slot ^ (row&7)).
  const ushort_t* pgA[2];
  const ushort_t* pgB[2];
#pragma unroll
  for (int q = 0; q < 2; ++q) {
    const int ch = q * 512 + tid;
    const int row = ch >> 3;             // 0..127 within half
    const int scol = ((ch & 7) ^ (row & 7)) * 8;
    pgA[q] = A + (size_t)(tile_row * 256 + row) * N + scol;
    pgB[q] = B + (size_t)(tile_col * 256 + row) * N + scol;
  }

#define GLD(SRC, DST)                                              \
  __builtin_amdgcn_global_load_lds(                                \
      (__attribute__((address_space(1))) void*)(SRC),              \
      (__attribute__((address_space(3))) void*)(DST), 16, 0, 0)
#define STG_A(H, KK, DSTB) {                                            \
    GLD(pgA[0] + (size_t)(H)*128*N + (KK), smem + (DSTB) + w*1024);     \
    GLD(pgA[1] + (size_t)(H)*128*N + (KK), smem + (DSTB) + 8192 + w*1024); }
#define STG_B(H, KK, DSTB) {                                            \
    GLD(pgB[0] + (size_t)(H)*128*N + (KK), smem + (DSTB) + w*1024);     \
    GLD(pgB[1] + (size_t)(H)*128*N + (KK), smem + (DSTB) + 8192 + w*1024); }

  // fragment read bases: row&7 == li&7 for every fragment row, so the
  // swizzled 16B-slot depends only on (sl, kh).
  const int rbA = (wr * 128 + li) * 128;
  const int rbB = 32768 + (wc * 64 + li) * 128;
  const int sb0 = ((sl) ^ (li & 7)) * 16;        // k-half 0
  const int sb1 = ((sl + 4) ^ (li & 7)) * 16;    // k-half 1

  bf16x8 aR[4][2], bR0[2][2], bR1[2][2];
  f32x4 acc[8][4];
#pragma unroll
  for (int m = 0; m < 8; ++m)
#pragma unroll
    for (int n = 0; n < 4; ++n) acc[m][n] = (f32x4){0.f, 0.f, 0.f, 0.f};

#define RDA(BUFB, QM) { _Pragma("unroll")                                      \
    for (int m = 0; m < 4; ++m) {                                              \
      aR[m][0] = *(const bf16x8*)(smem + (BUFB) + rbA + (QM)*8192 + m*2048 + sb0); \
      aR[m][1] = *(const bf16x8*)(smem + (BUFB) + rbA + (QM)*8192 + m*2048 + sb1); } }
#define RDB0(BUFB) { _Pragma("unroll")                                         \
    for (int n = 0; n < 2; ++n) {                                              \
      bR0[n][0] = *(const bf16x8*)(smem + (BUFB) + rbB + n*2048 + sb0);        \
      bR0[n][1] = *(const bf16x8*)(smem + (BUFB) + rbB + n*2048 + sb1); } }
#define RDB1(BUFB) { _Pragma("unroll")                                         \
    for (int n = 0; n < 2; ++n) {                                              \
      bR1[n][0] = *(const bf16x8*)(smem + (BUFB) + rbB + 4096 + n*2048 + sb0); \
      bR1[n][1] = *(const bf16x8*)(smem + (BUFB) + rbB + 4096 + n*2048 + sb1); } }

#define MFQ(QM, QN, BR) {                                                      \
    __builtin_amdgcn_s_setprio(1);                                             \
    _Pragma("unroll") for (int m = 0; m < 4; ++m)                              \
    _Pragma("unroll") for (int n = 0; n < 2; ++n) {                            \
      acc[(QM)*4+m][(QN)*2+n] = __builtin_amdgcn_mfma_f32_16x16x32_bf16(       \
          aR[m][0], BR[n][0], acc[(QM)*4+m][(QN)*2+n], 0, 0, 0);               \
      acc[(QM)*4+m][(QN)*2+n] = __builtin_amdgcn_mfma_f32_16x16x32_bf16(       \
          aR[m][1], BR[n][1], acc[(QM)*4+m][(QN)*2+n], 0, 0, 0); }             \
    __builtin_amdgcn_s_setprio(0); }

#define BARM __builtin_amdgcn_s_barrier();
#define BARC { __builtin_amdgcn_s_barrier(); __builtin_amdgcn_sched_barrier(0); }
#define LG   asm volatile("s_waitcnt lgkmcnt(0)" ::: "memory");
#define VM2  asm volatile("s_waitcnt vmcnt(2)" ::: "memory");
#define VM0  asm volatile("s_waitcnt vmcnt(0)" ::: "memory");

  // ---- prologue: T0 full -> buf0, T1.B0 -> buf1; gate T0 ----------------
  STG_A(0, 0, 0); STG_A(1, 0, 16384);
  STG_B(0, 0, 32768); STG_B(1, 0, 49152);
  STG_B(0, 64, 98304);
  VM2; BARC;

  // ---- main loop: iter k computes K-tiles 2k (buf0) and 2k+1 (buf1) -----
  // stages: ph1: T+1.B1  ph2: T+1.A0  ph3: T+1.A1   (-> buf1)
  //         ph4: T+2.A0  ph5: T+2.A1  ph6: T+2.B0  ph7: T+2.B1 (-> buf0)
  //         ph8: T+3.B0  (-> buf1);   vmcnt(2) gates at ph4 & ph8 only.
  for (int k = 0; k < 31; ++k) {
    const int kk0 = k * 128;
    // ph1
    RDA(0, 0); RDB0(0); STG_B(1, kk0 + 64, 114688);
    BARM; LG; MFQ(0, 0, bR0); BARC;
    // ph2
    RDB1(0); STG_A(0, kk0 + 64, 65536);
    BARM; LG; MFQ(0, 1, bR1); BARC;
    // ph3
    RDA(0, 1); STG_A(1, kk0 + 64, 81920);
    BARM; LG; MFQ(1, 0, bR0); BARC;
    // ph4
    STG_A(0, kk0 + 128, 0); VM2;
    BARM; LG; MFQ(1, 1, bR1); BARC;
    // ph5
    RDA(65536, 0); RDB0(65536); STG_A(1, kk0 + 128, 16384);
    BARM; LG; MFQ(0, 0, bR0); BARC;
    // ph6
    RDB1(65536); STG_B(0, kk0 + 128, 32768);
    BARM; LG; MFQ(0, 1, bR1); BARC;
    // ph7
    RDA(65536, 1); STG_B(1, kk0 + 128, 49152);
    BARM; LG; MFQ(1, 0, bR0); BARC;
    // ph8
    STG_B(0, kk0 + 192, 98304); VM2;
    BARM; LG; MFQ(1, 1, bR1); BARC;
  }

  // ---- tail: k = 31 (K-tiles 62, 63); stage only T63 halves -------------
  {
    const int kk0 = 31 * 128;
    RDA(0, 0); RDB0(0); STG_B(1, kk0 + 64, 114688);
    BARM; LG; MFQ(0, 0, bR0); BARC;
    RDB1(0); STG_A(0, kk0 + 64, 65536);
    BARM; LG; MFQ(0, 1, bR1); BARC;
    RDA(0, 1); STG_A(1, kk0 + 64, 81920);
    BARM; LG; MFQ(1, 0, bR0); BARC;
    VM0;
    BARM; LG; MFQ(1, 1, bR1); BARC;
    // phases 5-8: everything resident, no more LDS writes -> no barriers
    RDA(65536, 0); RDB0(65536);
    MFQ(0, 0, bR0);
    RDB1(65536);
    MFQ(0, 1, bR1);
    RDA(65536, 1);
    MFQ(1, 0, bR0);
    MFQ(1, 1, bR1);
  }

  // ---- epilogue: cosine normalize; C/D layout row=(l>>4)*4+r, col=l&15 --
  const float* nx = norms;
  const float* ny = norms + N;
  const int row0 = tile_row * 256 + wr * 128 + sl * 4;
  const int col0 = tile_col * 256 + wc * 64 + li;
#pragma unroll
  for (int m = 0; m < 8; ++m) {
#pragma unroll
    for (int r = 0; r < 4; ++r) {
      const int row = row0 + m * 16 + r;
      const float nxr = nx[row];
#pragma unroll
      for (int n = 0; n < 4; ++n) {
        const int col = col0 + n * 16;
        const float denom = fmaxf(nxr * ny[col], 1e-8f);
        out[(size_t)row * N + col] = acc[m][n][r] / denom;
      }
    }
  }
}

extern "C" void kernel_launch(void* const* d_in, const int* in_sizes, int n_in,
                              void* d_out, int out_size, void* d_ws, size_t ws_size,
                              hipStream_t stream) {
  const float* Z = (const float*)d_in[0];
  const float* Y = (const float*)d_in[1];
  float* out = (float*)d_out;

  ushort_t* Zb = (ushort_t*)d_ws;
  ushort_t* Yb = Zb + (size_t)N * N;
  float* norms = (float*)(Yb + (size_t)N * N);

  prep_kernel<<<2 * N, 256, 0, stream>>>(Z, Y, Zb, Yb, norms);
  gemm_kernel<<<(N / 256) * (N / 256), 512, 0, stream>>>(Zb, Yb, norms, out);
}